// Round 4
// baseline (72.268 us; speedup 1.0000x reference)
//
#include <hip/hip_runtime.h>

#define H 1024
#define W 1024
#define BATCH 16
#define SH 8                 // rows per wave-strip
#define WAVES 4              // waves per block (stacked vertically)
#define NT (WAVES * 64)      // 256 threads
#define BAND 256             // cols per wave (64 lanes x 4)
#define TILE_Y (WAVES * SH)  // 32
#define GXB (W / BAND)       // 4
#define GYB (H / TILE_Y)     // 32

// Target row: t[0..7] = tg[gy][gx-2 .. gx+5]; own float4 + shfl halos.
// Lanes 0/63 patch the cross-wave halo from global (L1-hot).
template<bool GR>
__device__ __forceinline__ void ld_tg(float t[8], const float* __restrict__ img,
                                      int gy, int gx, int lane) {
    bool rowok = true;
    if (GR) rowok = ((unsigned)gy < H);
    float4 v = make_float4(0.f, 0.f, 0.f, 0.f);
    if (rowok) v = *(const float4*)(img + (size_t)gy * W + gx);
    float lf2 = __shfl_up(v.z, 1);
    float lf1 = __shfl_up(v.w, 1);
    float rt0 = __shfl_down(v.x, 1);
    float rt1 = __shfl_down(v.y, 1);
    if (lane == 0) {
        lf2 = 0.f; lf1 = 0.f;
        if (rowok && gx >= 2) {
            const float* p = img + (size_t)gy * W + gx;
            lf2 = p[-2]; lf1 = p[-1];
        }
    }
    if (lane == 63) {
        rt0 = 0.f; rt1 = 0.f;
        if (rowok && gx + 5 < W) {
            const float* p = img + (size_t)gy * W + gx;
            rt0 = p[4]; rt1 = p[5];
        }
    }
    t[0] = lf2; t[1] = lf1; t[2] = v.x; t[3] = v.y;
    t[4] = v.z; t[5] = v.w; t[6] = rt0; t[7] = rt1;
}

// Input row: t[0..5] = in[gy][gx-1 .. gx+4]
template<bool GR>
__device__ __forceinline__ void ld_in(float t[6], const float* __restrict__ img,
                                      int gy, int gx, int lane) {
    bool rowok = true;
    if (GR) rowok = ((unsigned)gy < H);
    float4 v = make_float4(0.f, 0.f, 0.f, 0.f);
    if (rowok) v = *(const float4*)(img + (size_t)gy * W + gx);
    float lf1 = __shfl_up(v.w, 1);
    float rt0 = __shfl_down(v.x, 1);
    if (lane == 0)
        lf1 = (rowok && gx >= 1) ? img[(size_t)gy * W + gx - 1] : 0.f;
    if (lane == 63)
        rt0 = (rowok && gx + 4 < W) ? img[(size_t)gy * W + gx + 4] : 0.f;
    t[0] = lf1; t[1] = v.x; t[2] = v.y; t[3] = v.z; t[4] = v.w; t[5] = rt0;
}

// Squared Sobel row: 3 raw rows of 8 (idx k <-> col gx-2+k) -> 6 edge^2
// values (idx j <-> col gx-1+j). maxpool commutes with squaring.
__device__ __forceinline__ void edge2_6(const float a[8], const float b[8],
                                        const float c[8], float e2[6]) {
    float t2[8], dz[8];
    #pragma unroll
    for (int k = 0; k < 8; ++k) {
        t2[k] = fmaf(2.f, b[k], a[k] + c[k]);
        dz[k] = c[k] - a[k];
    }
    #pragma unroll
    for (int j = 0; j < 6; ++j) {
        float gxv = t2[j + 2] - t2[j];
        float gyv = fmaf(2.f, dz[j + 1], dz[j]) + dz[j + 2];
        e2[j] = fmaf(gyv, gyv, gxv * gxv);
    }
}

// Sobel magnitude row: 3 raw rows of 6 (idx k <-> col gx-1+k) -> 4 mags.
__device__ __forceinline__ void sobel4(const float a[6], const float b[6],
                                       const float c[6], float pe[4]) {
    float t2[6], dz[6];
    #pragma unroll
    for (int k = 0; k < 6; ++k) {
        t2[k] = fmaf(2.f, b[k], a[k] + c[k]);
        dz[k] = c[k] - a[k];
    }
    #pragma unroll
    for (int j = 0; j < 4; ++j) {
        float gxv = t2[j + 2] - t2[j];
        float gyv = fmaf(2.f, dz[j + 1], dz[j]) + dz[j + 2];
        pe[j] = sqrtf(fmaf(gyv, gyv, gxv * gxv));
    }
}

template<bool GR>
__device__ __forceinline__ float strip(const float* __restrict__ pIn,
                                       const float* __restrict__ pTg,
                                       int gx, int ty0, int lane) {
    const bool cz0 = (gx == 0);        // e2 col gx-1 is outside image
    const bool czL = (gx == W - 4);    // e2 col gx+4 is outside image

    float ta[8], tb[8], tc[8];         // rolling raw target rows
    float ia[6], ib[6], ic[6];         // rolling raw input rows
    float pm[6], ec[6], en[6];         // maxpool state: pairwise max + current

    // ---- prologue: e2 rows ty0-1 and ty0 ----
    float p0[8], p1[8], e0[6];
    ld_tg<GR>(p0, pTg, ty0 - 2, gx, lane);
    ld_tg<GR>(p1, pTg, ty0 - 1, gx, lane);
    ld_tg<GR>(ta, pTg, ty0,     gx, lane);
    edge2_6(p0, p1, ta, pm);           // e2 row ty0-1 (into pm for now)
    ld_tg<GR>(tb, pTg, ty0 + 1, gx, lane);
    edge2_6(p1, ta, tb, e0);           // e2 row ty0
    if (GR && ty0 == 0) {
        #pragma unroll
        for (int j = 0; j < 6; ++j) pm[j] = 0.f;
    }
    if (cz0) { pm[0] = 0.f; e0[0] = 0.f; }
    if (czL) { pm[5] = 0.f; e0[5] = 0.f; }
    #pragma unroll
    for (int j = 0; j < 6; ++j) { pm[j] = fmaxf(pm[j], e0[j]); ec[j] = e0[j]; }

    ld_in<GR>(ia, pIn, ty0 - 1, gx, lane);
    ld_in<GR>(ib, pIn, ty0,     gx, lane);

    // ---- main: one output row (4 px) per step ----
    float lsum = 0.f;
    #pragma unroll
    for (int r = 0; r < SH; ++r) {
        const int gy = ty0 + r;
        ld_tg<GR>(tc, pTg, gy + 2, gx, lane);
        edge2_6(ta, tb, tc, en);       // e2 row gy+1
        if (GR && (gy + 1 >= H)) {
            #pragma unroll
            for (int j = 0; j < 6; ++j) en[j] = 0.f;
        }
        if (cz0) en[0] = 0.f;
        if (czL) en[5] = 0.f;

        ld_in<GR>(ic, pIn, gy + 1, gx, lane);
        float pe[4];
        sobel4(ia, ib, ic, pe);        // pred edge row gy

        float m3[6];
        #pragma unroll
        for (int j = 0; j < 6; ++j) m3[j] = fmaxf(pm[j], en[j]);
        #pragma unroll
        for (int j = 0; j < 4; ++j) {
            float mp = fmaxf(fmaxf(m3[j], m3[j + 1]), m3[j + 2]);
            float d = pe[j] - 1.f;     // loss = maxpool(e^2) * (pe-1)^2
            lsum = fmaf(mp * d, d, lsum);
        }
        #pragma unroll
        for (int j = 0; j < 6; ++j) { pm[j] = fmaxf(ec[j], en[j]); ec[j] = en[j]; }
        #pragma unroll
        for (int k = 0; k < 8; ++k) { ta[k] = tb[k]; tb[k] = tc[k]; }
        #pragma unroll
        for (int k = 0; k < 6; ++k) { ia[k] = ib[k]; ib[k] = ic[k]; }
    }
    return lsum;
}

__global__ __launch_bounds__(NT) void edge_loss_main(
    const float* __restrict__ inp, const float* __restrict__ tgt,
    double* __restrict__ acc) {
    const int b = blockIdx.z;
    const float* pIn = inp + (size_t)b * (H * W);
    const float* pTg = tgt + (size_t)b * (H * W);
    const int tid  = threadIdx.x;
    const int lane = tid & 63;
    const int wave = tid >> 6;
    const int gx  = blockIdx.x * BAND + lane * 4;
    const int ty0 = blockIdx.y * TILE_Y + wave * SH;

    const bool gr = (blockIdx.y == 0) | (blockIdx.y == GYB - 1);
    float lsum = gr ? strip<true >(pIn, pTg, gx, ty0, lane)
                    : strip<false>(pIn, pTg, gx, ty0, lane);

    // ---- reduce: wave64 shuffle -> LDS -> one double atomicAdd per block ----
    #pragma unroll
    for (int off = 32; off > 0; off >>= 1)
        lsum += __shfl_down(lsum, off);
    __shared__ float wsum[WAVES];
    if (lane == 0) wsum[wave] = lsum;
    __syncthreads();
    if (tid == 0) {
        float bsum = 0.f;
        #pragma unroll
        for (int w2 = 0; w2 < WAVES; ++w2) bsum += wsum[w2];
        atomicAdd(acc, (double)bsum);
    }
}

__global__ void edge_loss_finalize(const double* __restrict__ acc,
                                   float* __restrict__ out) {
    out[0] = (float)(acc[0] / (double)((size_t)BATCH * H * W));
}

extern "C" void kernel_launch(void* const* d_in, const int* in_sizes, int n_in,
                              void* d_out, int out_size, void* d_ws, size_t ws_size,
                              hipStream_t stream) {
    const float* inputs  = (const float*)d_in[0];
    const float* targets = (const float*)d_in[1];
    float* out  = (float*)d_out;
    double* acc = (double*)d_ws;

    hipMemsetAsync(acc, 0, sizeof(double), stream);
    dim3 grid(GXB, GYB, BATCH);
    edge_loss_main<<<grid, NT, 0, stream>>>(inputs, targets, acc);
    edge_loss_finalize<<<1, 1, 0, stream>>>(acc, out);
}

// Round 5
// 68.726 us; speedup vs baseline: 1.0515x; 1.0515x over previous
//
#include <hip/hip_runtime.h>

#define H 1024
#define W 1024
#define BATCH 16
#define NT 256
#define NSLOTS 32
#define PXROW 128           // threads per image row (8 px each)

// ---- target row window: t[0..11] = tg[row][gx-2 .. gx+9] ----
__device__ __forceinline__ void ldtg(float t[12], const float* __restrict__ p,
                                     bool rowok, bool lok, bool rok) {
    #pragma unroll
    for (int k = 0; k < 12; ++k) t[k] = 0.f;
    if (rowok) {
        float2 a = lok ? *(const float2*)(p - 2) : make_float2(0.f, 0.f);
        float4 b = *(const float4*)p;
        float4 c = *(const float4*)(p + 4);
        float2 d = rok ? *(const float2*)(p + 8) : make_float2(0.f, 0.f);
        t[0] = a.x;  t[1] = a.y;
        t[2] = b.x;  t[3] = b.y;  t[4] = b.z;  t[5] = b.w;
        t[6] = c.x;  t[7] = c.y;  t[8] = c.z;  t[9] = c.w;
        t[10] = d.x; t[11] = d.y;
    }
}

// ---- input row window: t[0..9] = in[row][gx-1 .. gx+8] ----
__device__ __forceinline__ void ldin(float t[10], const float* __restrict__ p,
                                     bool rowok, bool lok, bool rok) {
    #pragma unroll
    for (int k = 0; k < 10; ++k) t[k] = 0.f;
    if (rowok) {
        float  a = lok ? p[-1] : 0.f;
        float4 b = *(const float4*)p;
        float4 c = *(const float4*)(p + 4);
        float  d = rok ? p[8] : 0.f;
        t[0] = a;
        t[1] = b.x; t[2] = b.y; t[3] = b.z; t[4] = b.w;
        t[5] = c.x; t[6] = c.y; t[7] = c.z; t[8] = c.w;
        t[9] = d;
    }
}

// ---- squared Sobel row from 3 raw rows of 12 (k <-> col gx-2+k), folded
// into running max m[j] (j <-> col gx-1+j). maxpool commutes with squaring. ----
__device__ __forceinline__ void e2fold(const float a[12], const float b[12],
                                       const float c[12], float m[10]) {
    float t2[12], dz[12];
    #pragma unroll
    for (int k = 0; k < 12; ++k) {
        t2[k] = fmaf(2.f, b[k], a[k] + c[k]);
        dz[k] = c[k] - a[k];
    }
    #pragma unroll
    for (int j = 0; j < 10; ++j) {
        float gxv = t2[j + 2] - t2[j];
        float gyv = fmaf(2.f, dz[j + 1], dz[j]) + dz[j + 2];
        m[j] = fmaxf(m[j], fmaf(gyv, gyv, gxv * gxv));
    }
}

// ---- pred-edge Sobel: 3 raw rows of 10 (k <-> col gx-1+k) -> 8 mags ----
__device__ __forceinline__ void sobel8(const float a[10], const float b[10],
                                       const float c[10], float pe[8]) {
    float t2[10], dz[10];
    #pragma unroll
    for (int k = 0; k < 10; ++k) {
        t2[k] = fmaf(2.f, b[k], a[k] + c[k]);
        dz[k] = c[k] - a[k];
    }
    #pragma unroll
    for (int j = 0; j < 8; ++j) {
        float gxv = t2[j + 2] - t2[j];
        float gyv = fmaf(2.f, dz[j + 1], dz[j]) + dz[j + 2];
        pe[j] = sqrtf(fmaf(gyv, gyv, gxv * gxv));
    }
}

template<bool GR>
__device__ __forceinline__ float rowtask(const float* __restrict__ pIn,
                                         const float* __restrict__ pTg,
                                         int gy, int px) {
    const int gx = px << 3;
    const bool lok = (px > 0);
    const bool rok = (px < PXROW - 1);
    const float* tgR = pTg + (size_t)gy * W + gx;
    const float* inR = pIn + (size_t)gy * W + gx;

    // ---- all loads issued up front (independent; 32-deep pipeline) ----
    float r0[12], r1[12], r2[12], r3[12], r4[12];
    float i0[10], i1[10], i2[10];
    ldtg(r0, tgR - 2 * W, !GR || (gy - 2 >= 0), lok, rok);
    ldtg(r1, tgR - 1 * W, !GR || (gy - 1 >= 0), lok, rok);
    ldtg(r2, tgR,         true,                 lok, rok);
    ldtg(r3, tgR + 1 * W, !GR || (gy + 1 < H),  lok, rok);
    ldtg(r4, tgR + 2 * W, !GR || (gy + 2 < H),  lok, rok);
    ldin(i0, inR - 1 * W, !GR || (gy - 1 >= 0), lok, rok);
    ldin(i1, inR,         true,                 lok, rok);
    ldin(i2, inR + 1 * W, !GR || (gy + 1 < H),  lok, rok);

    // ---- vertical-max fold of squared target-edge rows gy-1, gy, gy+1 ----
    float m[10];
    #pragma unroll
    for (int j = 0; j < 10; ++j) m[j] = 0.f;
    if (!GR || gy >= 1)     e2fold(r0, r1, r2, m);   // e2 row gy-1
    e2fold(r1, r2, r3, m);                           // e2 row gy
    if (!GR || gy <= H - 2) e2fold(r2, r3, r4, m);   // e2 row gy+1
    if (!lok) m[0] = 0.f;                            // e2 col gx-1 invalid
    if (!rok) m[9] = 0.f;                            // e2 col gx+8 invalid

    // ---- pred edge + horizontal max + loss ----
    float pe[8];
    sobel8(i0, i1, i2, pe);
    float ls0 = 0.f, ls1 = 0.f;
    #pragma unroll
    for (int j = 0; j < 8; ++j) {
        float mp = fmaxf(fmaxf(m[j], m[j + 1]), m[j + 2]);
        float d = pe[j] - 1.f;        // loss = maxpool(e^2) * (pe-1)^2
        if (j & 1) ls1 = fmaf(mp * d, d, ls1);
        else       ls0 = fmaf(mp * d, d, ls0);
    }
    return ls0 + ls1;
}

__global__ __launch_bounds__(NT) void edge_loss_main(
    const float* __restrict__ inp, const float* __restrict__ tgt,
    double* __restrict__ acc) {
    const int b   = blockIdx.y;
    const int tid = threadIdx.x;
    const int gy  = blockIdx.x * 2 + (tid >> 7);   // block = 2 image rows
    const int px  = tid & (PXROW - 1);
    const float* pIn = inp + (size_t)b * (H * W);
    const float* pTg = tgt + (size_t)b * (H * W);

    const bool gr = (blockIdx.x == 0) | (blockIdx.x == H / 2 - 1);
    float ls = gr ? rowtask<true >(pIn, pTg, gy, px)
                  : rowtask<false>(pIn, pTg, gy, px);

    // ---- reduce: wave64 shuffle -> LDS -> one double atomic per block ----
    #pragma unroll
    for (int off = 32; off > 0; off >>= 1)
        ls += __shfl_down(ls, off);
    __shared__ float wsum[NT / 64];
    const int wave = tid >> 6, lane = tid & 63;
    if (lane == 0) wsum[wave] = ls;
    __syncthreads();
    if (tid == 0) {
        float bsum = 0.f;
        #pragma unroll
        for (int w2 = 0; w2 < NT / 64; ++w2) bsum += wsum[w2];
        atomicAdd(&acc[blockIdx.x & (NSLOTS - 1)], (double)bsum);
    }
}

__global__ void edge_loss_finalize(const double* __restrict__ acc,
                                   float* __restrict__ out) {
    double s = 0.0;
    #pragma unroll
    for (int k = 0; k < NSLOTS; ++k) s += acc[k];
    out[0] = (float)(s / (double)((size_t)BATCH * H * W));
}

extern "C" void kernel_launch(void* const* d_in, const int* in_sizes, int n_in,
                              void* d_out, int out_size, void* d_ws, size_t ws_size,
                              hipStream_t stream) {
    const float* inputs  = (const float*)d_in[0];
    const float* targets = (const float*)d_in[1];
    float* out  = (float*)d_out;
    double* acc = (double*)d_ws;

    hipMemsetAsync(acc, 0, NSLOTS * sizeof(double), stream);
    dim3 grid(H / 2, BATCH);
    edge_loss_main<<<grid, NT, 0, stream>>>(inputs, targets, acc);
    edge_loss_finalize<<<1, 1, 0, stream>>>(acc, out);
}

// Round 6
// 45.695 us; speedup vs baseline: 1.5815x; 1.5040x over previous
//
#include <hip/hip_runtime.h>

#define H 1024
#define W 1024
#define BATCH 16
#define NT 256
#define NSLOTS 32
#define PXROW 128            // threads across one row-band (8 px each)
#define RPB 8                // image rows per block (2 bands x 4 rows)
#define NRB (H / RPB)        // 128 row-blocks per image
#define NBLK (NRB * BATCH)   // 2048 blocks
#define NXCD 8

// ---- target row window: t[0..11] = tg[row][gx-2 .. gx+9] ----
__device__ __forceinline__ void ldtg(float t[12], const float* __restrict__ p,
                                     bool rowok, bool lok, bool rok) {
    float2 a = make_float2(0.f, 0.f), d = make_float2(0.f, 0.f);
    float4 b = make_float4(0.f, 0.f, 0.f, 0.f), c = b;
    if (rowok) {
        if (lok) a = *(const float2*)(p - 2);
        b = *(const float4*)p;
        c = *(const float4*)(p + 4);
        if (rok) d = *(const float2*)(p + 8);
    }
    t[0] = a.x;  t[1] = a.y;
    t[2] = b.x;  t[3] = b.y;  t[4] = b.z;  t[5] = b.w;
    t[6] = c.x;  t[7] = c.y;  t[8] = c.z;  t[9] = c.w;
    t[10] = d.x; t[11] = d.y;
}

// ---- input row window: t[0..9] = in[row][gx-1 .. gx+8] ----
__device__ __forceinline__ void ldin(float t[10], const float* __restrict__ p,
                                     bool rowok, bool lok, bool rok) {
    float a = 0.f, d = 0.f;
    float4 b = make_float4(0.f, 0.f, 0.f, 0.f), c = b;
    if (rowok) {
        if (lok) a = p[-1];
        b = *(const float4*)p;
        c = *(const float4*)(p + 4);
        if (rok) d = p[8];
    }
    t[0] = a;
    t[1] = b.x; t[2] = b.y; t[3] = b.z; t[4] = b.w;
    t[5] = c.x; t[6] = c.y; t[7] = c.z; t[8] = c.w;
    t[9] = d;
}

// ---- squared Sobel row: 3 raw rows of 12 (k <-> col gx-2+k) -> 10 e2
// values (j <-> col gx-1+j). maxpool commutes with squaring. ----
__device__ __forceinline__ void e2row(const float a[12], const float b[12],
                                      const float c[12], float e[10]) {
    float t2[12], dz[12];
    #pragma unroll
    for (int k = 0; k < 12; ++k) {
        t2[k] = fmaf(2.f, b[k], a[k] + c[k]);
        dz[k] = c[k] - a[k];
    }
    #pragma unroll
    for (int j = 0; j < 10; ++j) {
        float gxv = t2[j + 2] - t2[j];
        float gyv = fmaf(2.f, dz[j + 1], dz[j]) + dz[j + 2];
        e[j] = fmaf(gyv, gyv, gxv * gxv);
    }
}

// ---- pred-edge Sobel: 3 raw rows of 10 (k <-> col gx-1+k) -> 8 mags ----
__device__ __forceinline__ void sobel8(const float a[10], const float b[10],
                                       const float c[10], float pe[8]) {
    float t2[10], dz[10];
    #pragma unroll
    for (int k = 0; k < 10; ++k) {
        t2[k] = fmaf(2.f, b[k], a[k] + c[k]);
        dz[k] = c[k] - a[k];
    }
    #pragma unroll
    for (int j = 0; j < 8; ++j) {
        float gxv = t2[j + 2] - t2[j];
        float gyv = fmaf(2.f, dz[j + 1], dz[j]) + dz[j + 2];
        pe[j] = sqrtf(fmaf(gyv, gyv, gxv * gxv));
    }
}

__device__ __forceinline__ void loss8(const float m[10], const float pe[8],
                                      float& ls) {
    #pragma unroll
    for (int j = 0; j < 8; ++j) {
        float mp = fmaxf(fmaxf(m[j], m[j + 1]), m[j + 2]);
        float d = pe[j] - 1.f;         // loss = maxpool(e^2) * (pe-1)^2
        ls = fmaf(mp * d, d, ls);
    }
}

#define FOLD1(M0)                                                   \
    { _Pragma("unroll") for (int j = 0; j < 10; ++j)                \
        M0[j] = fmaxf(M0[j], e[j]); }
#define FOLD2(M0, M1)                                               \
    { _Pragma("unroll") for (int j = 0; j < 10; ++j) {              \
        M0[j] = fmaxf(M0[j], e[j]); M1[j] = fmaxf(M1[j], e[j]); } }
#define FOLD3(M0, M1, M2)                                           \
    { _Pragma("unroll") for (int j = 0; j < 10; ++j) {              \
        M0[j] = fmaxf(M0[j], e[j]); M1[j] = fmaxf(M1[j], e[j]);     \
        M2[j] = fmaxf(M2[j], e[j]); } }

// One thread: 8 cols x 4 output rows (gy .. gy+3).
template<bool GR>
__device__ __forceinline__ float task4(const float* __restrict__ pIn,
                                       const float* __restrict__ pTg,
                                       int gy, int px) {
    const int gx = px << 3;
    const bool lok = (px > 0);
    const bool rok = (px < PXROW - 1);
    const float* tg = pTg + (size_t)gy * W + gx;
    const float* in = pIn + (size_t)gy * W + gx;

    float m0[10], m1[10], m2[10], m3[10];
    #pragma unroll
    for (int j = 0; j < 10; ++j) { m0[j] = 0.f; m1[j] = 0.f; m2[j] = 0.f; m3[j] = 0.f; }

    // ---- target phase: e2 rows gy-1 .. gy+4 folded into m0..m3 ----
    float A[12], Bv[12], C[12], D[12], e[10];
    ldtg(A,  tg - 2 * W, !GR || (gy >= 2), lok, rok);
    ldtg(Bv, tg - 1 * W, !GR || (gy >= 1), lok, rok);
    ldtg(C,  tg,          true,            lok, rok);
    ldtg(D,  tg + 1 * W,  true,            lok, rok);
    if (!GR || gy >= 1) {                  // e2 row gy-1
        e2row(A, Bv, C, e); FOLD1(m0);
    }
    ldtg(A, tg + 2 * W, true, lok, rok);   // raw gy+2 (<= H-2, valid)
    e2row(Bv, C, D, e); FOLD2(m0, m1);     // e2 row gy
    ldtg(Bv, tg + 3 * W, true, lok, rok);  // raw gy+3 (<= H-1, valid)
    e2row(C, D, A, e); FOLD3(m0, m1, m2);  // e2 row gy+1
    ldtg(C, tg + 4 * W, !GR || (gy + 4 < H), lok, rok);   // raw gy+4
    e2row(D, A, Bv, e); FOLD3(m1, m2, m3); // e2 row gy+2
    e2row(A, Bv, C, e); FOLD2(m2, m3);     // e2 row gy+3 (raw gy+4 zero-padded ok)
    if (!GR || (gy + 4 < H)) {             // e2 row gy+4 (excluded if OOB)
        ldtg(D, tg + 5 * W, !GR || (gy + 5 < H), lok, rok);
        e2row(Bv, C, D, e); FOLD1(m3);
    }
    if (!lok) { m0[0] = 0.f; m1[0] = 0.f; m2[0] = 0.f; m3[0] = 0.f; }
    if (!rok) { m0[9] = 0.f; m1[9] = 0.f; m2[9] = 0.f; m3[9] = 0.f; }

    // ---- input phase: pred-edge rows gy .. gy+3 + loss ----
    float IA[10], IB[10], IC[10], pe[8];
    float ls = 0.f;
    ldin(IA, in - 1 * W, !GR || (gy >= 1), lok, rok);
    ldin(IB, in,          true,            lok, rok);
    ldin(IC, in + 1 * W,  true,            lok, rok);
    sobel8(IA, IB, IC, pe); loss8(m0, pe, ls);          // row gy
    ldin(IA, in + 2 * W, true, lok, rok);
    sobel8(IB, IC, IA, pe); loss8(m1, pe, ls);          // row gy+1
    ldin(IB, in + 3 * W, true, lok, rok);
    sobel8(IC, IA, IB, pe); loss8(m2, pe, ls);          // row gy+2
    ldin(IC, in + 4 * W, !GR || (gy + 4 < H), lok, rok);
    sobel8(IA, IB, IC, pe); loss8(m3, pe, ls);          // row gy+3
    return ls;
}

__global__ __launch_bounds__(NT) void edge_loss_main(
    const float* __restrict__ inp, const float* __restrict__ tgt,
    double* __restrict__ acc) {
    // XCD-bijective swizzle: hw-consecutive blocks on one XCD become
    // image-adjacent row-blocks (NBLK % NXCD == 0 -> bijective).
    const int bid = blockIdx.x;
    const int lb  = (bid & (NXCD - 1)) * (NBLK / NXCD) + (bid >> 3);
    const int b      = lb >> 7;            // / NRB (128)
    const int rowblk = lb & (NRB - 1);

    const float* pIn = inp + (size_t)b * (H * W);
    const float* pTg = tgt + (size_t)b * (H * W);
    const int tid  = threadIdx.x;
    const int px   = tid & (PXROW - 1);
    const int band = tid >> 7;
    const int gy   = rowblk * RPB + band * 4;

    const bool gr = (rowblk == 0) | (rowblk == NRB - 1);
    float ls = gr ? task4<true >(pIn, pTg, gy, px)
                  : task4<false>(pIn, pTg, gy, px);

    // ---- reduce: wave64 shuffle -> LDS -> one double atomic per block ----
    #pragma unroll
    for (int off = 32; off > 0; off >>= 1)
        ls += __shfl_down(ls, off);
    __shared__ float wsum[NT / 64];
    const int wave = tid >> 6, lane = tid & 63;
    if (lane == 0) wsum[wave] = ls;
    __syncthreads();
    if (tid == 0) {
        float bsum = 0.f;
        #pragma unroll
        for (int w2 = 0; w2 < NT / 64; ++w2) bsum += wsum[w2];
        atomicAdd(&acc[bid & (NSLOTS - 1)], (double)bsum);
    }
}

__global__ void edge_loss_finalize(const double* __restrict__ acc,
                                   float* __restrict__ out) {
    double s = 0.0;
    #pragma unroll
    for (int k = 0; k < NSLOTS; ++k) s += acc[k];
    out[0] = (float)(s / (double)((size_t)BATCH * H * W));
}

extern "C" void kernel_launch(void* const* d_in, const int* in_sizes, int n_in,
                              void* d_out, int out_size, void* d_ws, size_t ws_size,
                              hipStream_t stream) {
    const float* inputs  = (const float*)d_in[0];
    const float* targets = (const float*)d_in[1];
    float* out  = (float*)d_out;
    double* acc = (double*)d_ws;

    hipMemsetAsync(acc, 0, NSLOTS * sizeof(double), stream);
    edge_loss_main<<<dim3(NBLK), NT, 0, stream>>>(inputs, targets, acc);
    edge_loss_finalize<<<1, 1, 0, stream>>>(acc, out);
}

// Round 7
// 41.441 us; speedup vs baseline: 1.7439x; 1.1027x over previous
//
#include <hip/hip_runtime.h>

#define H 1024
#define W 1024
#define BATCH 16
#define NT 256
#define NSLOTS 32
#define PXROW 128            // threads across one row-band (8 px each)
#define RPB 8                // image rows per block (2 bands x 4 rows)
#define NRB (H / RPB)        // 128 row-blocks per image
#define NBLK (NRB * BATCH)   // 2048 blocks
#define NXCD 8

typedef float v2 __attribute__((ext_vector_type(2)));

__device__ __forceinline__ v2 pmax2(v2 a, v2 b) {
#if __has_builtin(__builtin_elementwise_max)
    return __builtin_elementwise_max(a, b);
#else
    v2 r; r.x = fmaxf(a.x, b.x); r.y = fmaxf(a.y, b.y); return r;
#endif
}

// ---- 12-col window (cols gx-2 .. gx+9) as 6 column-pairs; pairs are
// naturally aligned: f2@gx-2 (8B-aligned), f4@gx, f4@gx+4, f2@gx+8. ----
__device__ __forceinline__ void ldw(v2 w[6], const float* __restrict__ p,
                                    bool rowok, bool lok, bool rok) {
    float2 a = make_float2(0.f, 0.f), d = make_float2(0.f, 0.f);
    float4 b = make_float4(0.f, 0.f, 0.f, 0.f), c = b;
    if (rowok) {
        if (lok) a = *(const float2*)(p - 2);
        b = *(const float4*)p;
        c = *(const float4*)(p + 4);
        if (rok) d = *(const float2*)(p + 8);
    }
    w[0].x = a.x; w[0].y = a.y;
    w[1].x = b.x; w[1].y = b.y;  w[2].x = b.z; w[2].y = b.w;
    w[3].x = c.x; w[3].y = c.y;  w[4].x = c.z; w[4].y = c.w;
    w[5].x = d.x; w[5].y = d.y;
}

// ---- packed squared-Sobel row: 3 raw windows (pairs, base gx-2) ->
// 5 pairs of squared magnitude on the odd-base grid (cols gx-1 .. gx+8).
// All shifts pair-aligned except one (dz odd shift -> 1 shuffle/pair).
// maxpool commutes with squaring, so no sqrt here. ----
__device__ __forceinline__ void e2pairs(const v2 a[6], const v2 b[6],
                                        const v2 c[6], v2 E[5]) {
    v2 t2[6], dz[6];
    #pragma unroll
    for (int k = 0; k < 6; ++k) {
        t2[k] = (a[k] + c[k]) + 2.0f * b[k];   // pk_add + pk_fma
        dz[k] = c[k] - a[k];
    }
    #pragma unroll
    for (int n = 0; n < 5; ++n) {
        v2 gxn = t2[n + 1] - t2[n];            // col shift +-1 == pair shift 1
        v2 sh;  sh.x = dz[n].y; sh.y = dz[n + 1].x;   // the one odd shift
        v2 gyn = (dz[n] + dz[n + 1]) + 2.0f * sh;
        E[n] = gxn * gxn + gyn * gyn;          // pk_mul + pk_fma
    }
}

// ---- scalar loss row: m[5] (pooled-e2 pairs) + S[5] (pe^2 pairs), both on
// the odd-base grid; output cols gx..gx+7 use components 1..8. ----
__device__ __forceinline__ void loss_row(const v2 m[5], const v2 S[5],
                                         float& ls) {
    float sm[10], spe[10];
    #pragma unroll
    for (int n = 0; n < 5; ++n) {
        sm[2 * n] = m[n].x;  sm[2 * n + 1] = m[n].y;
        spe[2 * n] = sqrtf(S[n].x);  spe[2 * n + 1] = sqrtf(S[n].y);
    }   // spe[0], spe[9] are dead -> DCE'd (8 live sqrt)
    #pragma unroll
    for (int c = 0; c < 8; ++c) {
        float mp = fmaxf(fmaxf(sm[c], sm[c + 1]), sm[c + 2]);
        float d = spe[c + 1] - 1.f;    // loss = maxpool(e^2) * (pe-1)^2
        ls = fmaf(mp * d, d, ls);
    }
}

#define FOLD1(M0)                                                    \
    { _Pragma("unroll") for (int n = 0; n < 5; ++n)                  \
        M0[n] = pmax2(M0[n], E[n]); }
#define FOLD2(M0, M1)                                                \
    { _Pragma("unroll") for (int n = 0; n < 5; ++n) {                \
        M0[n] = pmax2(M0[n], E[n]); M1[n] = pmax2(M1[n], E[n]); } }
#define FOLD3(M0, M1, M2)                                            \
    { _Pragma("unroll") for (int n = 0; n < 5; ++n) {                \
        M0[n] = pmax2(M0[n], E[n]); M1[n] = pmax2(M1[n], E[n]);      \
        M2[n] = pmax2(M2[n], E[n]); } }

// One thread: 8 cols x 4 output rows (gy .. gy+3).
template<bool GR>
__device__ __forceinline__ float task4(const float* __restrict__ pIn,
                                       const float* __restrict__ pTg,
                                       int gy, int px) {
    const int gx = px << 3;
    const bool lok = (px > 0);
    const bool rok = (px < PXROW - 1);
    const float* tg = pTg + (size_t)gy * W + gx;
    const float* in = pIn + (size_t)gy * W + gx;

    v2 m0[5], m1[5], m2[5], m3[5];
    #pragma unroll
    for (int n = 0; n < 5; ++n) {
        m0[n] = (v2)(0.f); m1[n] = (v2)(0.f);
        m2[n] = (v2)(0.f); m3[n] = (v2)(0.f);
    }

    // ---- target phase: e2 rows gy-1 .. gy+4 folded into m0..m3 ----
    v2 A[6], Bv[6], C[6], D[6], E[5];
    ldw(A,  tg - 2 * W, !GR || (gy >= 2), lok, rok);
    ldw(Bv, tg - 1 * W, !GR || (gy >= 1), lok, rok);
    ldw(C,  tg,          true,            lok, rok);
    ldw(D,  tg + 1 * W,  true,            lok, rok);
    if (!GR || gy >= 1) {                    // e2 row gy-1
        e2pairs(A, Bv, C, E); FOLD1(m0);
    }
    ldw(A, tg + 2 * W, true, lok, rok);      // raw gy+2 (always valid)
    e2pairs(Bv, C, D, E); FOLD2(m0, m1);     // e2 row gy
    ldw(Bv, tg + 3 * W, true, lok, rok);     // raw gy+3 (always valid)
    e2pairs(C, D, A, E); FOLD3(m0, m1, m2);  // e2 row gy+1
    ldw(C, tg + 4 * W, !GR || (gy + 4 < H), lok, rok);   // raw gy+4
    e2pairs(D, A, Bv, E); FOLD3(m1, m2, m3); // e2 row gy+2
    e2pairs(A, Bv, C, E); FOLD2(m2, m3);     // e2 row gy+3 (gy+4 zero-pad ok)
    if (!GR || (gy + 4 < H)) {               // e2 row gy+4 (excluded if OOB)
        ldw(D, tg + 5 * W, !GR || (gy + 5 < H), lok, rok);
        e2pairs(Bv, C, D, E); FOLD1(m3);
    }
    if (!lok) { m0[0].x = 0.f; m1[0].x = 0.f; m2[0].x = 0.f; m3[0].x = 0.f; }
    if (!rok) { m0[4].y = 0.f; m1[4].y = 0.f; m2[4].y = 0.f; m3[4].y = 0.f; }

    // ---- input phase: pe^2 rows gy .. gy+3 (packed) + scalar loss ----
    v2 IA[6], IB[6], IC[6], S[5];
    float ls = 0.f;
    ldw(IA, in - 1 * W, !GR || (gy >= 1), lok, rok);
    ldw(IB, in,          true,            lok, rok);
    ldw(IC, in + 1 * W,  true,            lok, rok);
    e2pairs(IA, IB, IC, S); loss_row(m0, S, ls);          // row gy
    ldw(IA, in + 2 * W, true, lok, rok);
    e2pairs(IB, IC, IA, S); loss_row(m1, S, ls);          // row gy+1
    ldw(IB, in + 3 * W, true, lok, rok);
    e2pairs(IC, IA, IB, S); loss_row(m2, S, ls);          // row gy+2
    ldw(IC, in + 4 * W, !GR || (gy + 4 < H), lok, rok);
    e2pairs(IA, IB, IC, S); loss_row(m3, S, ls);          // row gy+3
    return ls;
}

__global__ __launch_bounds__(NT) void edge_loss_main(
    const float* __restrict__ inp, const float* __restrict__ tgt,
    double* __restrict__ acc) {
    // XCD-bijective swizzle: hw-consecutive blocks on one XCD become
    // image-adjacent row-blocks (NBLK % NXCD == 0 -> bijective).
    const int bid = blockIdx.x;
    const int lb  = (bid & (NXCD - 1)) * (NBLK / NXCD) + (bid >> 3);
    const int b      = lb >> 7;            // / NRB (128)
    const int rowblk = lb & (NRB - 1);

    const float* pIn = inp + (size_t)b * (H * W);
    const float* pTg = tgt + (size_t)b * (H * W);
    const int tid  = threadIdx.x;
    const int px   = tid & (PXROW - 1);
    const int band = tid >> 7;
    const int gy   = rowblk * RPB + band * 4;

    const bool gr = (rowblk == 0) | (rowblk == NRB - 1);
    float ls = gr ? task4<true >(pIn, pTg, gy, px)
                  : task4<false>(pIn, pTg, gy, px);

    // ---- reduce: wave64 shuffle -> LDS -> one double atomic per block ----
    #pragma unroll
    for (int off = 32; off > 0; off >>= 1)
        ls += __shfl_down(ls, off);
    __shared__ float wsum[NT / 64];
    const int wave = tid >> 6, lane = tid & 63;
    if (lane == 0) wsum[wave] = ls;
    __syncthreads();
    if (tid == 0) {
        float bsum = 0.f;
        #pragma unroll
        for (int w2 = 0; w2 < NT / 64; ++w2) bsum += wsum[w2];
        atomicAdd(&acc[bid & (NSLOTS - 1)], (double)bsum);
    }
}

__global__ void edge_loss_finalize(const double* __restrict__ acc,
                                   float* __restrict__ out) {
    double s = 0.0;
    #pragma unroll
    for (int k = 0; k < NSLOTS; ++k) s += acc[k];
    out[0] = (float)(s / (double)((size_t)BATCH * H * W));
}

extern "C" void kernel_launch(void* const* d_in, const int* in_sizes, int n_in,
                              void* d_out, int out_size, void* d_ws, size_t ws_size,
                              hipStream_t stream) {
    const float* inputs  = (const float*)d_in[0];
    const float* targets = (const float*)d_in[1];
    float* out  = (float*)d_out;
    double* acc = (double*)d_ws;

    hipMemsetAsync(acc, 0, NSLOTS * sizeof(double), stream);
    edge_loss_main<<<dim3(NBLK), NT, 0, stream>>>(inputs, targets, acc);
    edge_loss_finalize<<<1, 1, 0, stream>>>(acc, out);
}